// Round 3
// baseline (2115.214 us; speedup 1.0000x reference)
//
#include <hip/hip_runtime.h>
#include <hip/hip_bf16.h>
#include <math.h>

// GGNN: L=5 layers of { m = h@W_l ; agg = scatter_add(ew * m[src] -> dst) ;
//                       h = GRUCell(agg, h) } then out = relu(h)@fc_w^T + fc_b
// H=256, N=50000, E=800000.
//
// R10: m97-faithful GEMM (128x128 tile, 4 waves x 4x4 16x16-tiles, BK=32).
// R11: skip dead MFMAs (structural-zero gate tiles, lo*lo cross terms).
// R12: BK=64 2-slab — gates 209->162 but m_gemm regressed; total flat.
// R13 (this round): T3 minimum pipeline. BK=32 chunks, TWO 24KB LDS slabs
// ping-pong; per chunk: { stage(c+1 -> other slab) ; ds_read+MFMA(c) ;
// __syncthreads() }. The vmcnt(0) drain the compiler emits at the barrier
// now lands AFTER compute, so HBM/L2 load latency overlaps the MFMA phase
// instead of sitting exposed between two barriers. One barrier per chunk.
// T5 setprio(1) around the MFMA cluster (pipeline gives waves role-split).

#define HDIM 256

using bf16x8 = __attribute__((ext_vector_type(8))) short;
using f32x4  = __attribute__((ext_vector_type(4))) float;

__device__ __forceinline__ bf16x8 ldfrag(const ushort* p) {
    union { uint4 u; bf16x8 f; } x;
    x.u = *(const uint4*)p;
    return x.f;
}
#define MFMA(a, b, c) __builtin_amdgcn_mfma_f32_16x16x32_bf16((a), (b), (c), 0, 0, 0)
#define GLD16(g, l)                                                            \
    __builtin_amdgcn_global_load_lds(                                          \
        (const __attribute__((address_space(1))) void*)(g),                    \
        (__attribute__((address_space(3))) void*)(l), 16, 0, 0)

__device__ __forceinline__ float ldf(const void* p, size_t i, int isbf) {
    if (isbf) return __bfloat162float(((const __hip_bfloat16*)p)[i]);
    return ((const float*)p)[i];
}
__device__ __forceinline__ ushort f2bs(float v) {
    __hip_bfloat16 b = __float2bfloat16(v);
    return *(ushort*)&b;
}
__device__ __forceinline__ float bs2f(ushort u) {
    __hip_bfloat16 b = *(__hip_bfloat16*)&u;
    return __bfloat162float(b);
}
// tiled plane addr, K-extent 256 (h planes): 16x32 fragment tiles of 512 halves
__device__ __forceinline__ size_t taddrH(int n, int k) {
    return (size_t)(n >> 4) * 4096 + (size_t)((k >> 5) << 9)
         + (size_t)(((k >> 3) & 3) << 7) + (size_t)((n & 15) << 3) + (k & 7);
}
// tiled plane addr, K-extent 512 (agg hi|lo combined)
__device__ __forceinline__ size_t taddrA(int n, int k) {
    return (size_t)(n >> 4) * 8192 + (size_t)((k >> 5) << 9)
         + (size_t)(((k >> 3) & 3) << 7) + (size_t)((n & 15) << 3) + (k & 7);
}

// flags[0] = 1 if float tensors are bf16, 0 if f32
// flags[1] = 1 if edge_index is int64, 0 if int32
__global__ void detect_k(const void* x, const void* ei, int* flags) {
    if (blockIdx.x == 0 && threadIdx.x == 0) {
        const __hip_bfloat16* xb = (const __hip_bfloat16*)x;
        int isbf = 1;
        for (int i = 0; i < 1024; ++i) {
            float v = fabsf(__bfloat162float(xb[i]));
            if (!(v < 1e6f)) { isbf = 0; break; }
        }
        flags[0] = isbf;
        const int* e32 = (const int*)ei;
        int orv = e32[1] | e32[3] | e32[5] | e32[7] | e32[9] | e32[11];
        flags[1] = (orv == 0) ? 1 : 0;
    }
}

// x -> h planes (tiled); pad rows zeroed
__global__ void conv_h0_k(const void* x, ushort* HH, ushort* HL,
                          const int* flags, int useHL, int Nn, size_t npad256) {
    size_t i = (size_t)blockIdx.x * blockDim.x + threadIdx.x;
    if (i >= npad256) return;
    const int n = (int)(i >> 8), k = (int)(i & 255);
    float v = 0.f;
    if (n < Nn) v = ldf(x, i, flags[0]);
    const ushort hi = f2bs(v);
    const size_t a = taddrH(n, k);
    HH[a] = hi;
    if (useHL) HL[a] = f2bs(v - bs2f(hi));
}

// Build tiled B matrices + biases.
// Bg [1024 out][1024 k] logical; out col j: q=j>>6, gate g=(j>>4)&3, b=16q+(j&15).
//   k seg 0/1 (agg hi/lo): g in {r,z,ni}: Wih[g*256+b][kk]; nh: 0
//   k seg 2/3 (h hi/lo):   g in {r,z}: Whh[...]; nh: Whh[512+b][kk]; ni: 0
// Bw [L][256 out][512 k]: Wt (both h hi/lo segs).
__global__ void prep_k(const void* w, const void* wih, const void* whh,
                       const void* bih, const void* bhh,
                       ushort* BgH, ushort* BgL, ushort* BwH, ushort* BwL,
                       float* bsum, float* bni, float* bnh,
                       const int* flags, int L) {
    int i = blockIdx.x * blockDim.x + threadIdx.x;
    int isbf = flags[0];
    if (i < 1048576) {
        const int j = i >> 10, k = i & 1023;
        const int g = (j >> 4) & 3, b = ((j >> 6) << 4) + (j & 15);
        const int kk = k & 255, seg = k >> 8;
        float v = 0.f;
        if (g == 0) v = (seg < 2) ? ldf(wih, (size_t)b * 256 + kk, isbf)
                                  : ldf(whh, (size_t)b * 256 + kk, isbf);
        else if (g == 1) v = (seg < 2) ? ldf(wih, (size_t)(256 + b) * 256 + kk, isbf)
                                       : ldf(whh, (size_t)(256 + b) * 256 + kk, isbf);
        else if (g == 2) v = (seg < 2) ? ldf(wih, (size_t)(512 + b) * 256 + kk, isbf) : 0.f;
        else             v = (seg < 2) ? 0.f : ldf(whh, (size_t)(512 + b) * 256 + kk, isbf);
        const ushort hi = f2bs(v);
        const int ct = j >> 4, c = k >> 5;
        const size_t a = (size_t)(ct * 32 + c) * 512
                       + (size_t)(((k >> 3) & 3) << 7) + ((j & 15) << 3) + (k & 7);
        BgH[a] = hi; BgL[a] = f2bs(v - bs2f(hi));
    }
    if (i < L * 131072) {
        const int l = i >> 17, r2 = i & 131071;
        const int j = r2 >> 9, k = r2 & 511;
        const int kk = k & 255;
        const float v = ldf(w, ((size_t)l << 16) + (size_t)kk * 256 + j, isbf);
        const ushort hi = f2bs(v);
        const int ct = j >> 4, c = k >> 5;
        const size_t a = (size_t)l * 131072 + (size_t)(ct * 16 + c) * 512
                       + (size_t)(((k >> 3) & 3) << 7) + ((j & 15) << 3) + (k & 7);
        BwH[a] = hi; BwL[a] = f2bs(v - bs2f(hi));
    }
    if (i < 512) bsum[i] = ldf(bih, i, isbf) + ldf(bhh, i, isbf);
    if (i < 256) {
        bni[i] = ldf(bih, 512 + i, isbf);
        bnh[i] = ldf(bhh, 512 + i, isbf);
    }
}

// ---------------- CSR build (by dst), once per call ----------------

__global__ void zero_int_k(int* p, int n) {
    int i = blockIdx.x * blockDim.x + threadIdx.x;
    if (i < n) p[i] = 0;
}

__global__ void count_k(const void* ei, int* cnt, const int* flags, int E) {
    int e = blockIdx.x * blockDim.x + threadIdx.x;
    if (e >= E) return;
    const int* e32 = (const int*)ei;
    int d = flags[1] ? e32[2 * ((size_t)E + e)] : e32[(size_t)E + e];
    atomicAdd(&cnt[d], 1);
}

__global__ __launch_bounds__(256)
void scan1_k(const int* cnt, int* ptr, int* bsumN, int N) {
    __shared__ int s[256];
    const int t = threadIdx.x;
    const int gid = blockIdx.x * 256 + t;
    int v = (gid < N) ? cnt[gid] : 0;
    const int own = v;
    s[t] = v;
    __syncthreads();
#pragma unroll
    for (int off = 1; off < 256; off <<= 1) {
        int add = (t >= off) ? s[t - off] : 0;
        __syncthreads();
        s[t] += add;
        __syncthreads();
    }
    if (gid < N) ptr[gid] = s[t] - own;
    if (t == 255) bsumN[blockIdx.x] = s[255];
}

__global__ __launch_bounds__(256)
void scan2_k(int* bsumN, int NB) {
    __shared__ int s[256];
    __shared__ int carry;
    const int t = threadIdx.x;
    if (t == 0) carry = 0;
    __syncthreads();
    for (int base = 0; base < NB; base += 256) {
        const int i = base + t;
        int v = (i < NB) ? bsumN[i] : 0;
        const int own = v;
        s[t] = v;
        __syncthreads();
#pragma unroll
        for (int off = 1; off < 256; off <<= 1) {
            int add = (t >= off) ? s[t - off] : 0;
            __syncthreads();
            s[t] += add;
            __syncthreads();
        }
        if (i < NB) bsumN[i] = carry + s[t] - own;
        __syncthreads();
        if (t == 0) carry += s[255];
        __syncthreads();
    }
}

__global__ void scan3_k(int* ptr, int* cursor, const int* bsumN, int N, int E) {
    const int gid = blockIdx.x * 256 + threadIdx.x;
    if (gid < N) {
        const int p = ptr[gid] + bsumN[blockIdx.x];
        ptr[gid] = p;
        cursor[gid] = p;
    }
    if (gid == 0) ptr[N] = E;
}

__global__ void fill_k(const void* ei, const void* ew, int* cursor,
                       int* srcs, float* wse, const int* flags, int E) {
    int e = blockIdx.x * blockDim.x + threadIdx.x;
    if (e >= E) return;
    const int* e32 = (const int*)ei;
    int s, d;
    if (flags[1]) { s = e32[2 * (size_t)e]; d = e32[2 * ((size_t)E + e)]; }
    else          { s = e32[e];             d = e32[(size_t)E + e]; }
    const int p = atomicAdd(&cursor[d], 1);
    srcs[p] = s;
    wse[p] = ldf(ew, e, flags[0]);
}

// ---------------- SpMM gather: agg[d] = sum_j w_j * m[src_j] ----------------
// Writes AGG combined plane (hi at k, lo at 256+k), tiled layout.
__global__ __launch_bounds__(256)
void spmm_k(const float* __restrict__ m, const int* __restrict__ ptr,
            const int* __restrict__ srcs, const float* __restrict__ wse,
            ushort* __restrict__ AGG, int N) {
    const int node = blockIdx.x * 4 + (threadIdx.x >> 6);
    if (node >= N) return;
    const int lane4 = (threadIdx.x & 63) << 2;
    const int p0 = ptr[node], p1 = ptr[node + 1];
    float4 acc = make_float4(0.f, 0.f, 0.f, 0.f);
    int j = p0;
    for (; j + 1 < p1; j += 2) {
        const int s0 = srcs[j], s1 = srcs[j + 1];
        const float w0 = wse[j], w1 = wse[j + 1];
        const float4 v0 = *(const float4*)&m[(size_t)s0 * HDIM + lane4];
        const float4 v1 = *(const float4*)&m[(size_t)s1 * HDIM + lane4];
        acc.x = fmaf(w0, v0.x, acc.x); acc.y = fmaf(w0, v0.y, acc.y);
        acc.z = fmaf(w0, v0.z, acc.z); acc.w = fmaf(w0, v0.w, acc.w);
        acc.x = fmaf(w1, v1.x, acc.x); acc.y = fmaf(w1, v1.y, acc.y);
        acc.z = fmaf(w1, v1.z, acc.z); acc.w = fmaf(w1, v1.w, acc.w);
    }
    if (j < p1) {
        const int s0 = srcs[j];
        const float w0 = wse[j];
        const float4 v0 = *(const float4*)&m[(size_t)s0 * HDIM + lane4];
        acc.x = fmaf(w0, v0.x, acc.x); acc.y = fmaf(w0, v0.y, acc.y);
        acc.z = fmaf(w0, v0.z, acc.z); acc.w = fmaf(w0, v0.w, acc.w);
    }
    ushort4 hi, lo;
    hi.x = f2bs(acc.x); lo.x = f2bs(acc.x - bs2f(hi.x));
    hi.y = f2bs(acc.y); lo.y = f2bs(acc.y - bs2f(hi.y));
    hi.z = f2bs(acc.z); lo.z = f2bs(acc.z - bs2f(hi.z));
    hi.w = f2bs(acc.w); lo.w = f2bs(acc.w - bs2f(hi.w));
    *(ushort4*)&AGG[taddrA(node, lane4)] = hi;
    *(ushort4*)&AGG[taddrA(node, 256 + lane4)] = lo;
}

// ---------------- m97-style GEMM #1: m = h @ Wt^T ---------------------------
// 128x128 tile, 4 waves (2x2 quadrants), 4x4 16x16-tiles per wave.
// R13: BK=32, double-buffered slabs, pipelined single barrier per chunk.
// chunks 0..7: A=hH (lo-B if fullsplit); 8..15: A=hL (no lo-B: lo*lo dropped).
__global__ __launch_bounds__(256)
void m_gemm_k(const ushort* __restrict__ HH, const ushort* __restrict__ HL,
              const ushort* __restrict__ BwHl, const ushort* __restrict__ BwLl,
              float* __restrict__ m, const int* __restrict__ flags,
              int useHL, int nRB) {
    __shared__ ushort lds[24576];  // 2 slabs x (A 4096 | Bh 4096 | Bl 4096)
    const int rb = blockIdx.x >> 1, cgB = blockIdx.x & 1;
    if (rb >= nRB) return;
    const int tid = threadIdx.x, lane = tid & 63;
    const int wv = __builtin_amdgcn_readfirstlane(tid >> 6);
    const int wr = wv & 1, wc = wv >> 1;
    const int lm = lane & 15, lq = lane >> 4;
    const int fullsplit = !flags[0];
    const int NCH = useHL ? 16 : 8;
    const int rt = rb * 8, t0 = 2 * wv;
    f32x4 acc[4][4];
#pragma unroll
    for (int i = 0; i < 4; ++i)
#pragma unroll
        for (int j = 0; j < 4; ++j) acc[i][j] = (f32x4){0.f, 0.f, 0.f, 0.f};

    auto stage = [&](int c, int sb) {
        const int lb = sb * 12288;
        const ushort* a0 = (c < 8)
            ? HH + (size_t)(rt + t0) * 4096 + (size_t)c * 512
            : HL + (size_t)(rt + t0) * 4096 + (size_t)(c - 8) * 512;
        GLD16(a0 + (size_t)lane * 8, &lds[lb + t0 * 512]);
        GLD16(a0 + 4096 + (size_t)lane * 8, &lds[lb + t0 * 512 + 512]);
        const size_t bb = ((size_t)(8 * cgB + t0) * 16 + (size_t)c) * 512;
        GLD16(BwHl + bb + (size_t)lane * 8, &lds[lb + 4096 + t0 * 512]);
        GLD16(BwHl + bb + 8192 + (size_t)lane * 8, &lds[lb + 4096 + t0 * 512 + 512]);
        if (fullsplit && c < 8) {
            GLD16(BwLl + bb + (size_t)lane * 8, &lds[lb + 8192 + t0 * 512]);
            GLD16(BwLl + bb + 8192 + (size_t)lane * 8, &lds[lb + 8192 + t0 * 512 + 512]);
        }
    };

    stage(0, 0);
    __syncthreads();
    for (int c = 0; c < NCH; ++c) {
        if (c + 1 < NCH) stage(c + 1, (c + 1) & 1);  // prefetch overlaps MFMA
        const int lb = (c & 1) * 12288;
        const int dolo = fullsplit && c < 8;
        bf16x8 af[4];
#pragma unroll
        for (int i = 0; i < 4; ++i)
            af[i] = ldfrag(&lds[lb + (4 * wr + i) * 512 + lq * 128 + lm * 8]);
        __builtin_amdgcn_s_setprio(1);
#pragma unroll
        for (int j = 0; j < 4; ++j) {
            const bf16x8 bj = ldfrag(&lds[lb + 4096 + (4 * wc + j) * 512 + lq * 128 + lm * 8]);
#pragma unroll
            for (int i = 0; i < 4; ++i) acc[i][j] = MFMA(af[i], bj, acc[i][j]);
        }
        if (dolo) {
#pragma unroll
            for (int j = 0; j < 4; ++j) {
                const bf16x8 bl = ldfrag(&lds[lb + 8192 + (4 * wc + j) * 512 + lq * 128 + lm * 8]);
#pragma unroll
                for (int i = 0; i < 4; ++i) acc[i][j] = MFMA(af[i], bl, acc[i][j]);
            }
        }
        __builtin_amdgcn_s_setprio(0);
        __syncthreads();  // drains prefetch (overlapped) + ds_reads
    }

#pragma unroll
    for (int i = 0; i < 4; ++i) {
        const int row = rb * 128 + wr * 64 + i * 16 + lq * 4;
#pragma unroll
        for (int j = 0; j < 4; ++j) {
            const int col = cgB * 128 + wc * 64 + j * 16 + lm;
#pragma unroll
            for (int v = 0; v < 4; ++v)
                m[(size_t)(row + v) * 256 + col] = acc[i][j][v];  // m is padded
        }
    }
}

// ---------------- m97-style GEMM #2: gates + fused GRU ----------------------
// A = [AGG(k 0..511) | hH(512..767) | hL(768..1023)], B = Bg (permuted).
// Wave's 4 col-tiles = (r,z,ni,nh) for 16 hidden units -> local GRU epilogue.
// Skips: jskip=3 (nh zero on agg K-segs, c<16), jskip=2 (ni zero on h K-segs,
// c>=16); lo-B pass only on A-hi regions (c<8, 16<=c<24). All wave-uniform.
// R13: BK=32 double-buffered slabs, pipelined single barrier per chunk.
__global__ __launch_bounds__(256)
void gates_k(const ushort* __restrict__ AGG,
             const ushort* __restrict__ HH, const ushort* __restrict__ HL,
             const ushort* __restrict__ BgH, const ushort* __restrict__ BgL,
             const float* __restrict__ bsum, const float* __restrict__ bni,
             const float* __restrict__ bnh,
             ushort* __restrict__ HnH, ushort* __restrict__ HnL,
             const int* __restrict__ flags, int useHL, int nRB) {
    __shared__ ushort lds[24576];  // 2 slabs x (A 4096 | Bh 4096 | Bl 4096)
    const int x = blockIdx.x & 7, rem = blockIdx.x >> 3;
    const int cgB = rem & 7, rbHi = rem >> 3;
    const int rb = rbHi * 8 + x;
    if (rb >= nRB) return;
    const int tid = threadIdx.x, lane = tid & 63;
    const int wv = __builtin_amdgcn_readfirstlane(tid >> 6);
    const int wr = wv & 1, wc = wv >> 1;
    const int lm = lane & 15, lq = lane >> 4;
    const int fullsplit = !flags[0];
    const int NCH = useHL ? 32 : 24;
    const int rt = rb * 8, t0 = 2 * wv;
    f32x4 acc[4][4];
#pragma unroll
    for (int i = 0; i < 4; ++i)
#pragma unroll
        for (int j = 0; j < 4; ++j) acc[i][j] = (f32x4){0.f, 0.f, 0.f, 0.f};

    auto stage = [&](int c, int sb) {
        const int lb = sb * 12288;
        const ushort* a0;
        size_t astride;
        if (c < 16)      { a0 = AGG + (size_t)(rt + t0) * 8192 + (size_t)c * 512; astride = 8192; }
        else if (c < 24) { a0 = HH + (size_t)(rt + t0) * 4096 + (size_t)(c - 16) * 512; astride = 4096; }
        else             { a0 = HL + (size_t)(rt + t0) * 4096 + (size_t)(c - 24) * 512; astride = 4096; }
        GLD16(a0 + (size_t)lane * 8, &lds[lb + t0 * 512]);
        GLD16(a0 + astride + (size_t)lane * 8, &lds[lb + t0 * 512 + 512]);
        const int jskip = (c < 16) ? 3 : 2;
        const size_t bb = ((size_t)(8 * cgB + t0) * 32 + (size_t)c) * 512;
        if ((t0 & 3) != jskip)
            GLD16(BgH + bb + (size_t)lane * 8, &lds[lb + 4096 + t0 * 512]);
        if (((t0 + 1) & 3) != jskip)
            GLD16(BgH + bb + 16384 + (size_t)lane * 8, &lds[lb + 4096 + t0 * 512 + 512]);
        const int dolo = fullsplit && (c < 8 || (c >= 16 && c < 24));
        if (dolo) {
            if ((t0 & 3) != jskip)
                GLD16(BgL + bb + (size_t)lane * 8, &lds[lb + 8192 + t0 * 512]);
            if (((t0 + 1) & 3) != jskip)
                GLD16(BgL + bb + 16384 + (size_t)lane * 8, &lds[lb + 8192 + t0 * 512 + 512]);
        }
    };

    stage(0, 0);
    __syncthreads();
    for (int c = 0; c < NCH; ++c) {
        if (c + 1 < NCH) stage(c + 1, (c + 1) & 1);  // prefetch overlaps MFMA
        const int lb = (c & 1) * 12288;
        const int jskip = (c < 16) ? 3 : 2;
        const int dolo = fullsplit && (c < 8 || (c >= 16 && c < 24));
        bf16x8 af[4];
#pragma unroll
        for (int i = 0; i < 4; ++i)
            af[i] = ldfrag(&lds[lb + (4 * wr + i) * 512 + lq * 128 + lm * 8]);
        __builtin_amdgcn_s_setprio(1);
#pragma unroll
        for (int j = 0; j < 4; ++j) {
            if (j == jskip) continue;  // wave-uniform structural-zero gate
            const bf16x8 bj = ldfrag(&lds[lb + 4096 + (4 * wc + j) * 512 + lq * 128 + lm * 8]);
#pragma unroll
            for (int i = 0; i < 4; ++i) acc[i][j] = MFMA(af[i], bj, acc[i][j]);
        }
        if (dolo) {
#pragma unroll
            for (int j = 0; j < 4; ++j) {
                if (j == jskip) continue;
                const bf16x8 bl = ldfrag(&lds[lb + 8192 + (4 * wc + j) * 512 + lq * 128 + lm * 8]);
#pragma unroll
                for (int i = 0; i < 4; ++i) acc[i][j] = MFMA(af[i], bl, acc[i][j]);
            }
        }
        __builtin_amdgcn_s_setprio(0);
        __syncthreads();  // drains prefetch (overlapped) + ds_reads
    }

    // GRU epilogue: col-tile 0..3 = r,z,ni,nh for hidden unit b
    const int b = (2 * cgB + wc) * 16 + lm;
    const float rbias = bsum[b], zbias = bsum[256 + b];
    const float ibias = bni[b], hbias = bnh[b];
#pragma unroll
    for (int i = 0; i < 4; ++i) {
        const int row0 = rb * 128 + wr * 64 + i * 16 + lq * 4;
#pragma unroll
        for (int v = 0; v < 4; ++v) {
            const int row = row0 + v;
            const size_t ho = taddrH(row, b);  // buffers padded; pads benign
            float hold = bs2f(HH[ho]);
            if (useHL) hold += bs2f(HL[ho]);
            const float r = 1.f / (1.f + expf(-(acc[i][0][v] + rbias)));
            const float z = 1.f / (1.f + expf(-(acc[i][1][v] + zbias)));
            const float nn = tanhf(acc[i][2][v] + ibias + r * (acc[i][3][v] + hbias));
            const float hv = (1.f - z) * nn + z * hold;
            const ushort hi = f2bs(hv);
            HnH[ho] = hi;
            if (useHL) HnL[ho] = f2bs(hv - bs2f(hi));
        }
    }
}

// out[n] = sum_t relu(h[n,t]) * fc_w[t] + fc_b ; one 256-thread block per node
__global__ void final_k(const ushort* __restrict__ HH, const ushort* __restrict__ HL,
                        const void* fcw, const void* fcb,
                        void* out, const int* flags, int useHL, int N) {
    const int n = blockIdx.x;
    const int t = threadIdx.x;
    const int isbf = flags[0];
    const size_t off = taddrH(n, t);
    float h = bs2f(HH[off]);
    if (useHL) h += bs2f(HL[off]);
    float v = fmaxf(h, 0.f) * ldf(fcw, t, isbf);
#pragma unroll
    for (int offx = 32; offx >= 1; offx >>= 1) v += __shfl_down(v, offx);
    __shared__ float red[4];
    if ((t & 63) == 0) red[t >> 6] = v;
    __syncthreads();
    if (t == 0) {
        const float s = red[0] + red[1] + red[2] + red[3] + ldf(fcb, 0, isbf);
        if (isbf) ((__hip_bfloat16*)out)[n] = __float2bfloat16(s);
        else      ((float*)out)[n] = s;
    }
}

extern "C" void kernel_launch(void* const* d_in, const int* in_sizes, int n_in,
                              void* d_out, int out_size, void* d_ws, size_t ws_size,
                              hipStream_t stream) {
    const int H = HDIM;
    const int N = in_sizes[0] / H;       // 50000
    const int E = in_sizes[2];           // 800000
    const int L = in_sizes[3] / (H * H); // 5
    const int NB = (N + 255) / 256;
    const int nRB = (N + 127) / 128;     // 391
    const size_t NPAD = (size_t)nRB * 128;
    const size_t hHalf = NPAD * 256;     // halves per h plane
    const size_t aggHalf = NPAD * 512;

    char* p = (char*)d_ws;
    int*    flags = (int*)p;              p += 64;
    ushort* AGG  = (ushort*)p;            p += aggHalf * 2;
    ushort* HxH  = (ushort*)p;            p += hHalf * 2;
    ushort* HyH  = (ushort*)p;            p += hHalf * 2;
    float*  m    = (float*)p;             p += NPAD * 256 * 4;
    ushort* BgH  = (ushort*)p;            p += (size_t)1048576 * 2;
    ushort* BgL  = (ushort*)p;            p += (size_t)1048576 * 2;
    ushort* BwH  = (ushort*)p;            p += (size_t)L * 131072 * 2;
    ushort* BwL  = (ushort*)p;            p += (size_t)L * 131072 * 2;
    float*  bsum = (float*)p;             p += 512 * 4;
    float*  bni  = (float*)p;             p += 256 * 4;
    float*  bnh  = (float*)p;             p += 256 * 4;
    int*    ptr  = (int*)p;               p += (size_t)(N + 1) * 4;
    int*    cursor = (int*)p;             p += (size_t)N * 4;
    int*    bsumN  = (int*)p;             p += (size_t)NB * 4;
    int*    srcs   = (int*)p;             p += (size_t)E * 4;
    float*  wse    = (float*)p;           p += (size_t)E * 4;
    const size_t need_reduced = (size_t)(p - (char*)d_ws);
    ushort* HxL = (ushort*)p;             // optional hi/lo h planes
    ushort* HyL = (ushort*)(p + hHalf * 2);
    const size_t need_full = need_reduced + 2 * hHalf * 2;
    const int useHL = (ws_size >= need_full) ? 1 : 0;
    if (!useHL) { HxL = HxH; HyL = HyH; }  // never dereferenced when useHL=0

    detect_k<<<dim3(1), dim3(64), 0, stream>>>(d_in[0], d_in[1], flags);
    conv_h0_k<<<dim3((unsigned)NPAD), dim3(256), 0, stream>>>(
        d_in[0], HxH, HxL, flags, useHL, N, NPAD * 256);
    prep_k<<<dim3(4096), dim3(256), 0, stream>>>(
        d_in[3], d_in[4], d_in[5], d_in[6], d_in[7],
        BgH, BgL, BwH, BwL, bsum, bni, bnh, flags, L);

    zero_int_k<<<dim3(NB), dim3(256), 0, stream>>>(cursor, N);
    count_k<<<dim3((E + 255) / 256), dim3(256), 0, stream>>>(d_in[1], cursor, flags, E);
    scan1_k<<<dim3(NB), dim3(256), 0, stream>>>(cursor, ptr, bsumN, N);
    scan2_k<<<dim3(1), dim3(256), 0, stream>>>(bsumN, NB);
    scan3_k<<<dim3(NB), dim3(256), 0, stream>>>(ptr, cursor, bsumN, N, E);
    fill_k<<<dim3((E + 255) / 256), dim3(256), 0, stream>>>(
        d_in[1], d_in[2], cursor, srcs, wse, flags, E);

    const dim3 blk(256);
    const unsigned gGrid = 64u * (unsigned)((nRB + 7) / 8);
    ushort *HcH = HxH, *HcL = HxL, *HnH = HyH, *HnL = HyL;
    for (int l = 0; l < L; ++l) {
        m_gemm_k<<<dim3((unsigned)(2 * nRB)), blk, 0, stream>>>(
            HcH, HcL, BwH + (size_t)l * 131072, BwL + (size_t)l * 131072,
            m, flags, useHL, nRB);
        spmm_k<<<dim3((N + 3) / 4), blk, 0, stream>>>(m, ptr, srcs, wse, AGG, N);
        gates_k<<<dim3(gGrid), blk, 0, stream>>>(
            AGG, HcH, HcL, BgH, BgL, bsum, bni, bnh, HnH, HnL, flags, useHL, nRB);
        ushort* t;
        t = HcH; HcH = HnH; HnH = t;
        t = HcL; HcL = HnL; HnL = t;
    }
    final_k<<<dim3(N), blk, 0, stream>>>(
        HcH, HcL, d_in[8], d_in[9], d_out, flags, useHL, N);
}

// Round 4
// 1998.520 us; speedup vs baseline: 1.0584x; 1.0584x over previous
//
#include <hip/hip_runtime.h>
#include <hip/hip_bf16.h>
#include <math.h>

// GGNN: L=5 layers of { m = h@W_l ; agg = scatter_add(ew * m[src] -> dst) ;
//                       h = GRUCell(agg, h) } then out = relu(h)@fc_w^T + fc_b
// H=256, N=50000, E=800000.
//
// R10: m97-faithful GEMM (128x128 tile, 4 waves x 4x4 16x16-tiles, BK=32).
// R11: skip dead MFMAs (structural-zero gate tiles, lo*lo cross terms).
// R12: gates BK=64 2-slab: 209->162us. m_gemm BK=64 regressed (+47us/disp).
// R13: drain-0 ping-pong pipeline: REGRESSED (barrier vmcnt(0) drains the
//      just-issued prefetch -> same exposed latency, lost BK=64 amortization).
// R14 (this round): best-of mix. gates_k = R12 (BK=64 2-slab, proven 162us);
//      m_gemm_k = R11 (BK=32 2-barrier, proven via rest-accounting ~35us).
//      No new schedule semantics.

#define HDIM 256

using bf16x8 = __attribute__((ext_vector_type(8))) short;
using f32x4  = __attribute__((ext_vector_type(4))) float;

__device__ __forceinline__ bf16x8 ldfrag(const ushort* p) {
    union { uint4 u; bf16x8 f; } x;
    x.u = *(const uint4*)p;
    return x.f;
}
#define MFMA(a, b, c) __builtin_amdgcn_mfma_f32_16x16x32_bf16((a), (b), (c), 0, 0, 0)
#define GLD16(g, l)                                                            \
    __builtin_amdgcn_global_load_lds(                                          \
        (const __attribute__((address_space(1))) void*)(g),                    \
        (__attribute__((address_space(3))) void*)(l), 16, 0, 0)

__device__ __forceinline__ float ldf(const void* p, size_t i, int isbf) {
    if (isbf) return __bfloat162float(((const __hip_bfloat16*)p)[i]);
    return ((const float*)p)[i];
}
__device__ __forceinline__ ushort f2bs(float v) {
    __hip_bfloat16 b = __float2bfloat16(v);
    return *(ushort*)&b;
}
__device__ __forceinline__ float bs2f(ushort u) {
    __hip_bfloat16 b = *(__hip_bfloat16*)&u;
    return __bfloat162float(b);
}
// tiled plane addr, K-extent 256 (h planes): 16x32 fragment tiles of 512 halves
__device__ __forceinline__ size_t taddrH(int n, int k) {
    return (size_t)(n >> 4) * 4096 + (size_t)((k >> 5) << 9)
         + (size_t)(((k >> 3) & 3) << 7) + (size_t)((n & 15) << 3) + (k & 7);
}
// tiled plane addr, K-extent 512 (agg hi|lo combined)
__device__ __forceinline__ size_t taddrA(int n, int k) {
    return (size_t)(n >> 4) * 8192 + (size_t)((k >> 5) << 9)
         + (size_t)(((k >> 3) & 3) << 7) + (size_t)((n & 15) << 3) + (k & 7);
}

// flags[0] = 1 if float tensors are bf16, 0 if f32
// flags[1] = 1 if edge_index is int64, 0 if int32
__global__ void detect_k(const void* x, const void* ei, int* flags) {
    if (blockIdx.x == 0 && threadIdx.x == 0) {
        const __hip_bfloat16* xb = (const __hip_bfloat16*)x;
        int isbf = 1;
        for (int i = 0; i < 1024; ++i) {
            float v = fabsf(__bfloat162float(xb[i]));
            if (!(v < 1e6f)) { isbf = 0; break; }
        }
        flags[0] = isbf;
        const int* e32 = (const int*)ei;
        int orv = e32[1] | e32[3] | e32[5] | e32[7] | e32[9] | e32[11];
        flags[1] = (orv == 0) ? 1 : 0;
    }
}

// x -> h planes (tiled); pad rows zeroed
__global__ void conv_h0_k(const void* x, ushort* HH, ushort* HL,
                          const int* flags, int useHL, int Nn, size_t npad256) {
    size_t i = (size_t)blockIdx.x * blockDim.x + threadIdx.x;
    if (i >= npad256) return;
    const int n = (int)(i >> 8), k = (int)(i & 255);
    float v = 0.f;
    if (n < Nn) v = ldf(x, i, flags[0]);
    const ushort hi = f2bs(v);
    const size_t a = taddrH(n, k);
    HH[a] = hi;
    if (useHL) HL[a] = f2bs(v - bs2f(hi));
}

// Build tiled B matrices + biases.
// Bg [1024 out][1024 k] logical; out col j: q=j>>6, gate g=(j>>4)&3, b=16q+(j&15).
//   k seg 0/1 (agg hi/lo): g in {r,z,ni}: Wih[g*256+b][kk]; nh: 0
//   k seg 2/3 (h hi/lo):   g in {r,z}: Whh[...]; nh: Whh[512+b][kk]; ni: 0
// Bw [L][256 out][512 k]: Wt (both h hi/lo segs).
__global__ void prep_k(const void* w, const void* wih, const void* whh,
                       const void* bih, const void* bhh,
                       ushort* BgH, ushort* BgL, ushort* BwH, ushort* BwL,
                       float* bsum, float* bni, float* bnh,
                       const int* flags, int L) {
    int i = blockIdx.x * blockDim.x + threadIdx.x;
    int isbf = flags[0];
    if (i < 1048576) {
        const int j = i >> 10, k = i & 1023;
        const int g = (j >> 4) & 3, b = ((j >> 6) << 4) + (j & 15);
        const int kk = k & 255, seg = k >> 8;
        float v = 0.f;
        if (g == 0) v = (seg < 2) ? ldf(wih, (size_t)b * 256 + kk, isbf)
                                  : ldf(whh, (size_t)b * 256 + kk, isbf);
        else if (g == 1) v = (seg < 2) ? ldf(wih, (size_t)(256 + b) * 256 + kk, isbf)
                                       : ldf(whh, (size_t)(256 + b) * 256 + kk, isbf);
        else if (g == 2) v = (seg < 2) ? ldf(wih, (size_t)(512 + b) * 256 + kk, isbf) : 0.f;
        else             v = (seg < 2) ? 0.f : ldf(whh, (size_t)(512 + b) * 256 + kk, isbf);
        const ushort hi = f2bs(v);
        const int ct = j >> 4, c = k >> 5;
        const size_t a = (size_t)(ct * 32 + c) * 512
                       + (size_t)(((k >> 3) & 3) << 7) + ((j & 15) << 3) + (k & 7);
        BgH[a] = hi; BgL[a] = f2bs(v - bs2f(hi));
    }
    if (i < L * 131072) {
        const int l = i >> 17, r2 = i & 131071;
        const int j = r2 >> 9, k = r2 & 511;
        const int kk = k & 255;
        const float v = ldf(w, ((size_t)l << 16) + (size_t)kk * 256 + j, isbf);
        const ushort hi = f2bs(v);
        const int ct = j >> 4, c = k >> 5;
        const size_t a = (size_t)l * 131072 + (size_t)(ct * 16 + c) * 512
                       + (size_t)(((k >> 3) & 3) << 7) + ((j & 15) << 3) + (k & 7);
        BwH[a] = hi; BwL[a] = f2bs(v - bs2f(hi));
    }
    if (i < 512) bsum[i] = ldf(bih, i, isbf) + ldf(bhh, i, isbf);
    if (i < 256) {
        bni[i] = ldf(bih, 512 + i, isbf);
        bnh[i] = ldf(bhh, 512 + i, isbf);
    }
}

// ---------------- CSR build (by dst), once per call ----------------

__global__ void zero_int_k(int* p, int n) {
    int i = blockIdx.x * blockDim.x + threadIdx.x;
    if (i < n) p[i] = 0;
}

__global__ void count_k(const void* ei, int* cnt, const int* flags, int E) {
    int e = blockIdx.x * blockDim.x + threadIdx.x;
    if (e >= E) return;
    const int* e32 = (const int*)ei;
    int d = flags[1] ? e32[2 * ((size_t)E + e)] : e32[(size_t)E + e];
    atomicAdd(&cnt[d], 1);
}

__global__ __launch_bounds__(256)
void scan1_k(const int* cnt, int* ptr, int* bsumN, int N) {
    __shared__ int s[256];
    const int t = threadIdx.x;
    const int gid = blockIdx.x * 256 + t;
    int v = (gid < N) ? cnt[gid] : 0;
    const int own = v;
    s[t] = v;
    __syncthreads();
#pragma unroll
    for (int off = 1; off < 256; off <<= 1) {
        int add = (t >= off) ? s[t - off] : 0;
        __syncthreads();
        s[t] += add;
        __syncthreads();
    }
    if (gid < N) ptr[gid] = s[t] - own;
    if (t == 255) bsumN[blockIdx.x] = s[255];
}

__global__ __launch_bounds__(256)
void scan2_k(int* bsumN, int NB) {
    __shared__ int s[256];
    __shared__ int carry;
    const int t = threadIdx.x;
    if (t == 0) carry = 0;
    __syncthreads();
    for (int base = 0; base < NB; base += 256) {
        const int i = base + t;
        int v = (i < NB) ? bsumN[i] : 0;
        const int own = v;
        s[t] = v;
        __syncthreads();
#pragma unroll
        for (int off = 1; off < 256; off <<= 1) {
            int add = (t >= off) ? s[t - off] : 0;
            __syncthreads();
            s[t] += add;
            __syncthreads();
        }
        if (i < NB) bsumN[i] = carry + s[t] - own;
        __syncthreads();
        if (t == 0) carry += s[255];
        __syncthreads();
    }
}

__global__ void scan3_k(int* ptr, int* cursor, const int* bsumN, int N, int E) {
    const int gid = blockIdx.x * 256 + threadIdx.x;
    if (gid < N) {
        const int p = ptr[gid] + bsumN[blockIdx.x];
        ptr[gid] = p;
        cursor[gid] = p;
    }
    if (gid == 0) ptr[N] = E;
}

__global__ void fill_k(const void* ei, const void* ew, int* cursor,
                       int* srcs, float* wse, const int* flags, int E) {
    int e = blockIdx.x * blockDim.x + threadIdx.x;
    if (e >= E) return;
    const int* e32 = (const int*)ei;
    int s, d;
    if (flags[1]) { s = e32[2 * (size_t)e]; d = e32[2 * ((size_t)E + e)]; }
    else          { s = e32[e];             d = e32[(size_t)E + e]; }
    const int p = atomicAdd(&cursor[d], 1);
    srcs[p] = s;
    wse[p] = ldf(ew, e, flags[0]);
}

// ---------------- SpMM gather: agg[d] = sum_j w_j * m[src_j] ----------------
// Writes AGG combined plane (hi at k, lo at 256+k), tiled layout.
__global__ __launch_bounds__(256)
void spmm_k(const float* __restrict__ m, const int* __restrict__ ptr,
            const int* __restrict__ srcs, const float* __restrict__ wse,
            ushort* __restrict__ AGG, int N) {
    const int node = blockIdx.x * 4 + (threadIdx.x >> 6);
    if (node >= N) return;
    const int lane4 = (threadIdx.x & 63) << 2;
    const int p0 = ptr[node], p1 = ptr[node + 1];
    float4 acc = make_float4(0.f, 0.f, 0.f, 0.f);
    int j = p0;
    for (; j + 1 < p1; j += 2) {
        const int s0 = srcs[j], s1 = srcs[j + 1];
        const float w0 = wse[j], w1 = wse[j + 1];
        const float4 v0 = *(const float4*)&m[(size_t)s0 * HDIM + lane4];
        const float4 v1 = *(const float4*)&m[(size_t)s1 * HDIM + lane4];
        acc.x = fmaf(w0, v0.x, acc.x); acc.y = fmaf(w0, v0.y, acc.y);
        acc.z = fmaf(w0, v0.z, acc.z); acc.w = fmaf(w0, v0.w, acc.w);
        acc.x = fmaf(w1, v1.x, acc.x); acc.y = fmaf(w1, v1.y, acc.y);
        acc.z = fmaf(w1, v1.z, acc.z); acc.w = fmaf(w1, v1.w, acc.w);
    }
    if (j < p1) {
        const int s0 = srcs[j];
        const float w0 = wse[j];
        const float4 v0 = *(const float4*)&m[(size_t)s0 * HDIM + lane4];
        acc.x = fmaf(w0, v0.x, acc.x); acc.y = fmaf(w0, v0.y, acc.y);
        acc.z = fmaf(w0, v0.z, acc.z); acc.w = fmaf(w0, v0.w, acc.w);
    }
    ushort4 hi, lo;
    hi.x = f2bs(acc.x); lo.x = f2bs(acc.x - bs2f(hi.x));
    hi.y = f2bs(acc.y); lo.y = f2bs(acc.y - bs2f(hi.y));
    hi.z = f2bs(acc.z); lo.z = f2bs(acc.z - bs2f(hi.z));
    hi.w = f2bs(acc.w); lo.w = f2bs(acc.w - bs2f(hi.w));
    *(ushort4*)&AGG[taddrA(node, lane4)] = hi;
    *(ushort4*)&AGG[taddrA(node, 256 + lane4)] = lo;
}

// ---------------- m97-style GEMM #1: m = h @ Wt^T ---------------------------
// 128x128 tile, 4 waves (2x2 quadrants), 4x4 16x16-tiles per wave (64 acc
// f32/thread). BK=32; A+B tiles glds-staged; 2 barriers/chunk. (R11 variant —
// the proven-best m_gemm.) BwL (lo-B) pass only on hH chunks (skip lo*lo).
__global__ __launch_bounds__(256)
void m_gemm_k(const ushort* __restrict__ HH, const ushort* __restrict__ HL,
              const ushort* __restrict__ BwHl, const ushort* __restrict__ BwLl,
              float* __restrict__ m, const int* __restrict__ flags,
              int useHL, int nRB) {
    __shared__ ushort lds[12288];  // A 4096 | Bh 4096 | Bl 4096 halves (24KB)
    const int rb = blockIdx.x >> 1, cgB = blockIdx.x & 1;
    if (rb >= nRB) return;
    const int tid = threadIdx.x, lane = tid & 63;
    const int wv = __builtin_amdgcn_readfirstlane(tid >> 6);
    const int wr = wv & 1, wc = wv >> 1;
    const int lm = lane & 15, lq = lane >> 4;
    const int fullsplit = !flags[0];
    const int rt = rb * 8, t0 = 2 * wv;
    f32x4 acc[4][4];
#pragma unroll
    for (int i = 0; i < 4; ++i)
#pragma unroll
        for (int j = 0; j < 4; ++j) acc[i][j] = (f32x4){0.f, 0.f, 0.f, 0.f};

#define MG_CHUNK(c, A0, DOLO)                                                  \
    do {                                                                       \
        __syncthreads();                                                       \
        GLD16((A0) + (size_t)lane * 8, &lds[t0 * 512]);                        \
        GLD16((A0) + 4096 + (size_t)lane * 8, &lds[t0 * 512 + 512]);           \
        const size_t bb = ((size_t)(8 * cgB + t0) * 16 + (size_t)(c)) * 512;   \
        GLD16(BwHl + bb + (size_t)lane * 8, &lds[4096 + t0 * 512]);            \
        GLD16(BwHl + bb + 8192 + (size_t)lane * 8, &lds[4096 + t0 * 512 + 512]); \
        if (DOLO) {                                                            \
            GLD16(BwLl + bb + (size_t)lane * 8, &lds[8192 + t0 * 512]);        \
            GLD16(BwLl + bb + 8192 + (size_t)lane * 8, &lds[8192 + t0 * 512 + 512]); \
        }                                                                      \
        __syncthreads();                                                       \
        bf16x8 af[4], bfh[4];                                                  \
        _Pragma("unroll")                                                      \
        for (int i = 0; i < 4; ++i)                                            \
            af[i] = ldfrag(&lds[(4 * wr + i) * 512 + lq * 128 + lm * 8]);      \
        _Pragma("unroll")                                                      \
        for (int j = 0; j < 4; ++j)                                            \
            bfh[j] = ldfrag(&lds[4096 + (4 * wc + j) * 512 + lq * 128 + lm * 8]); \
        _Pragma("unroll")                                                      \
        for (int i = 0; i < 4; ++i)                                            \
            _Pragma("unroll")                                                  \
            for (int j = 0; j < 4; ++j) acc[i][j] = MFMA(af[i], bfh[j], acc[i][j]); \
        if (DOLO) {                                                            \
            _Pragma("unroll")                                                  \
            for (int j = 0; j < 4; ++j) {                                      \
                const bf16x8 bl = ldfrag(&lds[8192 + (4 * wc + j) * 512 + lq * 128 + lm * 8]); \
                _Pragma("unroll")                                              \
                for (int i = 0; i < 4; ++i) acc[i][j] = MFMA(af[i], bl, acc[i][j]); \
            }                                                                  \
        }                                                                      \
    } while (0)

    for (int c = 0; c < 8; ++c) {
        const ushort* a0 = HH + (size_t)(rt + t0) * 4096 + (size_t)c * 512;
        MG_CHUNK(c, a0, fullsplit);
    }
    if (useHL) {
        for (int c = 8; c < 16; ++c) {
            const ushort* a0 = HL + (size_t)(rt + t0) * 4096 + (size_t)(c - 8) * 512;
            MG_CHUNK(c, a0, 0);
        }
    }
#undef MG_CHUNK

#pragma unroll
    for (int i = 0; i < 4; ++i) {
        const int row = rb * 128 + wr * 64 + i * 16 + lq * 4;
#pragma unroll
        for (int j = 0; j < 4; ++j) {
            const int col = cgB * 128 + wc * 64 + j * 16 + lm;
#pragma unroll
            for (int v = 0; v < 4; ++v)
                m[(size_t)(row + v) * 256 + col] = acc[i][j][v];  // m is padded
        }
    }
}

// ---------------- m97-style GEMM #2: gates + fused GRU ----------------------
// A = [AGG(k 0..511) | hH(512..767) | hL(768..1023)], B = Bg (permuted).
// Wave's 4 col-tiles = (r,z,ni,nh) for 16 hidden units -> local GRU epilogue.
// R11 skips: JSKIP=3 (nh zero on agg K-segs), JSKIP=2 (ni zero on h K-segs);
// lo-B pass only on A-hi regions. R12: BK=64, two slabs per barrier pair
// (48KB LDS), 16 steps total. (Proven-best gates: 162us.)
__global__ __launch_bounds__(256)
void gates_k(const ushort* __restrict__ AGG,
             const ushort* __restrict__ HH, const ushort* __restrict__ HL,
             const ushort* __restrict__ BgH, const ushort* __restrict__ BgL,
             const float* __restrict__ bsum, const float* __restrict__ bni,
             const float* __restrict__ bnh,
             ushort* __restrict__ HnH, ushort* __restrict__ HnL,
             const int* __restrict__ flags, int useHL, int nRB) {
    __shared__ ushort lds[24576];  // 2 slabs x (A 4096 | Bh 4096 | Bl 4096)
    const int x = blockIdx.x & 7, rem = blockIdx.x >> 3;
    const int cgB = rem & 7, rbHi = rem >> 3;
    const int rb = rbHi * 8 + x;
    if (rb >= nRB) return;
    const int tid = threadIdx.x, lane = tid & 63;
    const int wv = __builtin_amdgcn_readfirstlane(tid >> 6);
    const int wr = wv & 1, wc = wv >> 1;
    const int lm = lane & 15, lq = lane >> 4;
    const int fullsplit = !flags[0];
    const int rt = rb * 8, t0 = 2 * wv;
    f32x4 acc[4][4];
#pragma unroll
    for (int i = 0; i < 4; ++i)
#pragma unroll
        for (int j = 0; j < 4; ++j) acc[i][j] = (f32x4){0.f, 0.f, 0.f, 0.f};

// One BK=64 step = chunks c0, c0+1. JSKIP: gate col-tile with structurally
// zero B in this K-region -> no MFMA, no staging of its strips.
// Bg: consecutive chunk -> +512; next ct row -> +16384.
#define GT_STEP(c0, A0, ASTRIDE, JSKIP, DOLO)                                  \
    do {                                                                       \
        __syncthreads();                                                       \
        GLD16((A0) + (size_t)lane * 8, &lds[t0 * 512]);                        \
        GLD16((A0) + (ASTRIDE) + (size_t)lane * 8, &lds[t0 * 512 + 512]);      \
        GLD16((A0) + 512 + (size_t)lane * 8, &lds[12288 + t0 * 512]);          \
        GLD16((A0) + (ASTRIDE) + 512 + (size_t)lane * 8, &lds[12288 + t0 * 512 + 512]); \
        const size_t bb = ((size_t)(8 * cgB + t0) * 32 + (size_t)(c0)) * 512;  \
        if ((t0 & 3) != (JSKIP)) {                                             \
            GLD16(BgH + bb + (size_t)lane * 8, &lds[4096 + t0 * 512]);         \
            GLD16(BgH + bb + 512 + (size_t)lane * 8, &lds[12288 + 4096 + t0 * 512]); \
        }                                                                      \
        if (((t0 + 1) & 3) != (JSKIP)) {                                       \
            GLD16(BgH + bb + 16384 + (size_t)lane * 8, &lds[4096 + t0 * 512 + 512]); \
            GLD16(BgH + bb + 16896 + (size_t)lane * 8, &lds[12288 + 4096 + t0 * 512 + 512]); \
        }                                                                      \
        if (DOLO) {                                                            \
            if ((t0 & 3) != (JSKIP)) {                                         \
                GLD16(BgL + bb + (size_t)lane * 8, &lds[8192 + t0 * 512]);     \
                GLD16(BgL + bb + 512 + (size_t)lane * 8, &lds[12288 + 8192 + t0 * 512]); \
            }                                                                  \
            if (((t0 + 1) & 3) != (JSKIP)) {                                   \
                GLD16(BgL + bb + 16384 + (size_t)lane * 8, &lds[8192 + t0 * 512 + 512]); \
                GLD16(BgL + bb + 16896 + (size_t)lane * 8, &lds[12288 + 8192 + t0 * 512 + 512]); \
            }                                                                  \
        }                                                                      \
        __syncthreads();                                                       \
        _Pragma("unroll")                                                      \
        for (int sb = 0; sb < 2; ++sb) {                                       \
            const int lb = sb * 12288;                                         \
            bf16x8 af[4];                                                      \
            _Pragma("unroll")                                                  \
            for (int i = 0; i < 4; ++i)                                        \
                af[i] = ldfrag(&lds[lb + (4 * wr + i) * 512 + lq * 128 + lm * 8]); \
            _Pragma("unroll")                                                  \
            for (int j = 0; j < 4; ++j) {                                      \
                if (j == (JSKIP)) continue;                                    \
                const bf16x8 bj = ldfrag(&lds[lb + 4096 + (4 * wc + j) * 512 + lq * 128 + lm * 8]); \
                _Pragma("unroll")                                              \
                for (int i = 0; i < 4; ++i) acc[i][j] = MFMA(af[i], bj, acc[i][j]); \
            }                                                                  \
            if (DOLO) {                                                        \
                _Pragma("unroll")                                              \
                for (int j = 0; j < 4; ++j) {                                  \
                    if (j == (JSKIP)) continue;                                \
                    const bf16x8 bl = ldfrag(&lds[lb + 8192 + (4 * wc + j) * 512 + lq * 128 + lm * 8]); \
                    _Pragma("unroll")                                          \
                    for (int i = 0; i < 4; ++i) acc[i][j] = MFMA(af[i], bl, acc[i][j]); \
                }                                                              \
            }                                                                  \
        }                                                                      \
    } while (0)

    // region 0: chunks 0..7   A = AGG hi (gates r,z,ni; lo-B if fullsplit)
    for (int s = 0; s < 4; ++s) {
        const ushort* a0 = AGG + (size_t)(rt + t0) * 8192 + (size_t)(2 * s) * 512;
        GT_STEP(2 * s, a0, 8192, 3, fullsplit);
    }
    // region 1: chunks 8..15  A = AGG lo (no lo-B: lo*lo dropped)
    for (int s = 4; s < 8; ++s) {
        const ushort* a0 = AGG + (size_t)(rt + t0) * 8192 + (size_t)(2 * s) * 512;
        GT_STEP(2 * s, a0, 8192, 3, 0);
    }
    // region 2: chunks 16..23 A = hH (gates r,z,nh; lo-B if fullsplit)
    for (int s = 8; s < 12; ++s) {
        const ushort* a0 = HH + (size_t)(rt + t0) * 4096 + (size_t)(2 * s - 16) * 512;
        GT_STEP(2 * s, a0, 4096, 2, fullsplit);
    }
    // region 3: chunks 24..31 A = hL (no lo-B)
    if (useHL) {
        for (int s = 12; s < 16; ++s) {
            const ushort* a0 = HL + (size_t)(rt + t0) * 4096 + (size_t)(2 * s - 24) * 512;
            GT_STEP(2 * s, a0, 4096, 2, 0);
        }
    }
#undef GT_STEP

    // GRU epilogue: col-tile 0..3 = r,z,ni,nh for hidden unit b
    const int b = (2 * cgB + wc) * 16 + lm;
    const float rbias = bsum[b], zbias = bsum[256 + b];
    const float ibias = bni[b], hbias = bnh[b];
#pragma unroll
    for (int i = 0; i < 4; ++i) {
        const int row0 = rb * 128 + wr * 64 + i * 16 + lq * 4;
#pragma unroll
        for (int v = 0; v < 4; ++v) {
            const int row = row0 + v;
            const size_t ho = taddrH(row, b);  // buffers padded; pads benign
            float hold = bs2f(HH[ho]);
            if (useHL) hold += bs2f(HL[ho]);
            const float r = 1.f / (1.f + expf(-(acc[i][0][v] + rbias)));
            const float z = 1.f / (1.f + expf(-(acc[i][1][v] + zbias)));
            const float nn = tanhf(acc[i][2][v] + ibias + r * (acc[i][3][v] + hbias));
            const float hv = (1.f - z) * nn + z * hold;
            const ushort hi = f2bs(hv);
            HnH[ho] = hi;
            if (useHL) HnL[ho] = f2bs(hv - bs2f(hi));
        }
    }
}

// out[n] = sum_t relu(h[n,t]) * fc_w[t] + fc_b ; one 256-thread block per node
__global__ void final_k(const ushort* __restrict__ HH, const ushort* __restrict__ HL,
                        const void* fcw, const void* fcb,
                        void* out, const int* flags, int useHL, int N) {
    const int n = blockIdx.x;
    const int t = threadIdx.x;
    const int isbf = flags[0];
    const size_t off = taddrH(n, t);
    float h = bs2f(HH[off]);
    if (useHL) h += bs2f(HL[off]);
    float v = fmaxf(h, 0.f) * ldf(fcw, t, isbf);
#pragma unroll
    for (int offx = 32; offx >= 1; offx >>= 1) v += __shfl_down(v, offx);
    __shared__ float red[4];
    if ((t & 63) == 0) red[t >> 6] = v;
    __syncthreads();
    if (t == 0) {
        const float s = red[0] + red[1] + red[2] + red[3] + ldf(fcb, 0, isbf);
        if (isbf) ((__hip_bfloat16*)out)[n] = __float2bfloat16(s);
        else      ((float*)out)[n] = s;
    }
}

extern "C" void kernel_launch(void* const* d_in, const int* in_sizes, int n_in,
                              void* d_out, int out_size, void* d_ws, size_t ws_size,
                              hipStream_t stream) {
    const int H = HDIM;
    const int N = in_sizes[0] / H;       // 50000
    const int E = in_sizes[2];           // 800000
    const int L = in_sizes[3] / (H * H); // 5
    const int NB = (N + 255) / 256;
    const int nRB = (N + 127) / 128;     // 391
    const size_t NPAD = (size_t)nRB * 128;
    const size_t hHalf = NPAD * 256;     // halves per h plane
    const size_t aggHalf = NPAD * 512;

    char* p = (char*)d_ws;
    int*    flags = (int*)p;              p += 64;
    ushort* AGG  = (ushort*)p;            p += aggHalf * 2;
    ushort* HxH  = (ushort*)p;            p += hHalf * 2;
    ushort* HyH  = (ushort*)p;            p += hHalf * 2;
    float*  m    = (float*)p;             p += NPAD * 256 * 4;
    ushort* BgH  = (ushort*)p;            p += (size_t)1048576 * 2;
    ushort* BgL  = (ushort*)p;            p += (size_t)1048576 * 2;
    ushort* BwH  = (ushort*)p;            p += (size_t)L * 131072 * 2;
    ushort* BwL  = (ushort*)p;            p += (size_t)L * 131072 * 2;
    float*  bsum = (float*)p;             p += 512 * 4;
    float*  bni  = (float*)p;             p += 256 * 4;
    float*  bnh  = (float*)p;             p += 256 * 4;
    int*    ptr  = (int*)p;               p += (size_t)(N + 1) * 4;
    int*    cursor = (int*)p;             p += (size_t)N * 4;
    int*    bsumN  = (int*)p;             p += (size_t)NB * 4;
    int*    srcs   = (int*)p;             p += (size_t)E * 4;
    float*  wse    = (float*)p;           p += (size_t)E * 4;
    const size_t need_reduced = (size_t)(p - (char*)d_ws);
    ushort* HxL = (ushort*)p;             // optional hi/lo h planes
    ushort* HyL = (ushort*)(p + hHalf * 2);
    const size_t need_full = need_reduced + 2 * hHalf * 2;
    const int useHL = (ws_size >= need_full) ? 1 : 0;
    if (!useHL) { HxL = HxH; HyL = HyH; }  // never dereferenced when useHL=0

    detect_k<<<dim3(1), dim3(64), 0, stream>>>(d_in[0], d_in[1], flags);
    conv_h0_k<<<dim3((unsigned)NPAD), dim3(256), 0, stream>>>(
        d_in[0], HxH, HxL, flags, useHL, N, NPAD * 256);
    prep_k<<<dim3(4096), dim3(256), 0, stream>>>(
        d_in[3], d_in[4], d_in[5], d_in[6], d_in[7],
        BgH, BgL, BwH, BwL, bsum, bni, bnh, flags, L);

    zero_int_k<<<dim3(NB), dim3(256), 0, stream>>>(cursor, N);
    count_k<<<dim3((E + 255) / 256), dim3(256), 0, stream>>>(d_in[1], cursor, flags, E);
    scan1_k<<<dim3(NB), dim3(256), 0, stream>>>(cursor, ptr, bsumN, N);
    scan2_k<<<dim3(1), dim3(256), 0, stream>>>(bsumN, NB);
    scan3_k<<<dim3(NB), dim3(256), 0, stream>>>(ptr, cursor, bsumN, N, E);
    fill_k<<<dim3((E + 255) / 256), dim3(256), 0, stream>>>(
        d_in[1], d_in[2], cursor, srcs, wse, flags, E);

    const dim3 blk(256);
    const unsigned gGrid = 64u * (unsigned)((nRB + 7) / 8);
    ushort *HcH = HxH, *HcL = HxL, *HnH = HyH, *HnL = HyL;
    for (int l = 0; l < L; ++l) {
        m_gemm_k<<<dim3((unsigned)(2 * nRB)), blk, 0, stream>>>(
            HcH, HcL, BwH + (size_t)l * 131072, BwL + (size_t)l * 131072,
            m, flags, useHL, nRB);
        spmm_k<<<dim3((N + 3) / 4), blk, 0, stream>>>(m, ptr, srcs, wse, AGG, N);
        gates_k<<<dim3(gGrid), blk, 0, stream>>>(
            AGG, HcH, HcL, BgH, BgL, bsum, bni, bnh, HnH, HnL, flags, useHL, nRB);
        ushort* t;
        t = HcH; HcH = HnH; HnH = t;
        t = HcL; HcL = HnL; HnL = t;
    }
    final_k<<<dim3(N), blk, 0, stream>>>(
        HcH, HcL, d_in[8], d_in[9], d_out, flags, useHL, N);
}

// Round 5
// 1884.016 us; speedup vs baseline: 1.1227x; 1.0608x over previous
//
#include <hip/hip_runtime.h>
#include <hip/hip_bf16.h>
#include <math.h>

// GGNN: L=5 layers of { m = h@W_l ; agg = scatter_add(ew * m[src] -> dst) ;
//                       h = GRUCell(agg, h) } then out = relu(h)@fc_w^T + fc_b
// H=256, N=50000, E=800000.
//
// R10-R14: m97-style gates GEMM (128x128 tile, BK=64 2-slab, dead-MFMA skips)
// proven at 162us/dispatch.
// R15 (this round): WEIGHT FOLDING deletes m_gemm. Scatter and GEMM commute:
//   agg = sum_e w_e (h[src] @ W_l) = (sum_e w_e h[src]) @ W_l = S @ W_l
//   gi  = agg @ Wih^T = S @ (Wih @ W_l^T)^T = S @ WihP_l^T
// prep computes WihP_l = Wih @ W_l^T (f32, tiny) and builds per-layer Bg agg
// segments from it; layer loop is now { spmm(h) -> gates }. spmm gathers h
// as packed (hi|lo) bf16 uints (h_lin, 1KB/row coalesced), written by the
// gates epilogue. One fewer split-bf16 GEMM stage in the error path.

#define HDIM 256

using bf16x8 = __attribute__((ext_vector_type(8))) short;
using f32x4  = __attribute__((ext_vector_type(4))) float;

__device__ __forceinline__ bf16x8 ldfrag(const ushort* p) {
    union { uint4 u; bf16x8 f; } x;
    x.u = *(const uint4*)p;
    return x.f;
}
#define MFMA(a, b, c) __builtin_amdgcn_mfma_f32_16x16x32_bf16((a), (b), (c), 0, 0, 0)
#define GLD16(g, l)                                                            \
    __builtin_amdgcn_global_load_lds(                                          \
        (const __attribute__((address_space(1))) void*)(g),                    \
        (__attribute__((address_space(3))) void*)(l), 16, 0, 0)

__device__ __forceinline__ float ldf(const void* p, size_t i, int isbf) {
    if (isbf) return __bfloat162float(((const __hip_bfloat16*)p)[i]);
    return ((const float*)p)[i];
}
__device__ __forceinline__ ushort f2bs(float v) {
    __hip_bfloat16 b = __float2bfloat16(v);
    return *(ushort*)&b;
}
__device__ __forceinline__ float bs2f(ushort u) {
    __hip_bfloat16 b = *(__hip_bfloat16*)&u;
    return __bfloat162float(b);
}
// packed (hi|lo) pair -> f32 value. hi bits in low 16, lo bits in high 16.
__device__ __forceinline__ float unpk(uint u) {
    return __uint_as_float(u << 16) + __uint_as_float(u & 0xffff0000u);
}
__device__ __forceinline__ uint pk(float v) {
    const ushort hi = f2bs(v);
    const ushort lo = f2bs(v - bs2f(hi));
    return (uint)hi | ((uint)lo << 16);
}
// tiled plane addr, K-extent 256 (h planes): 16x32 fragment tiles of 512 halves
__device__ __forceinline__ size_t taddrH(int n, int k) {
    return (size_t)(n >> 4) * 4096 + (size_t)((k >> 5) << 9)
         + (size_t)(((k >> 3) & 3) << 7) + (size_t)((n & 15) << 3) + (k & 7);
}
// tiled plane addr, K-extent 512 (S hi|lo combined)
__device__ __forceinline__ size_t taddrA(int n, int k) {
    return (size_t)(n >> 4) * 8192 + (size_t)((k >> 5) << 9)
         + (size_t)(((k >> 3) & 3) << 7) + (size_t)((n & 15) << 3) + (k & 7);
}

// flags[0] = 1 if float tensors are bf16, 0 if f32
// flags[1] = 1 if edge_index is int64, 0 if int32
__global__ void detect_k(const void* x, const void* ei, int* flags) {
    if (blockIdx.x == 0 && threadIdx.x == 0) {
        const __hip_bfloat16* xb = (const __hip_bfloat16*)x;
        int isbf = 1;
        for (int i = 0; i < 1024; ++i) {
            float v = fabsf(__bfloat162float(xb[i]));
            if (!(v < 1e6f)) { isbf = 0; break; }
        }
        flags[0] = isbf;
        const int* e32 = (const int*)ei;
        int orv = e32[1] | e32[3] | e32[5] | e32[7] | e32[9] | e32[11];
        flags[1] = (orv == 0) ? 1 : 0;
    }
}

// x -> h planes (tiled) + h_lin packed; pad rows zeroed
__global__ void conv_h0_k(const void* x, ushort* HH, ushort* HL, uint* hlin,
                          const int* flags, int useHL, int Nn, size_t npad256) {
    size_t i = (size_t)blockIdx.x * blockDim.x + threadIdx.x;
    if (i >= npad256) return;
    const int n = (int)(i >> 8), k = (int)(i & 255);
    float v = 0.f;
    if (n < Nn) v = ldf(x, i, flags[0]);
    const ushort hi = f2bs(v);
    const size_t a = taddrH(n, k);
    HH[a] = hi;
    if (useHL) HL[a] = f2bs(v - bs2f(hi));
    hlin[i] = (uint)hi | ((uint)f2bs(v - bs2f(hi)) << 16);
}

// WihP[l][r][k] = sum_j Wih[r][j] * W[l][k][j]  (f32, 16x16-tiled, LDS-staged)
__global__ __launch_bounds__(256)
void prep1_k(const void* wih, const void* w, float* wihp, const int* flags) {
    __shared__ float As[16][260], Bs[16][260];
    const int bx = blockIdx.x;            // l*768 + rt16*16 + kt16
    const int l = bx / 768, rem = bx % 768;
    const int rt = (rem >> 4) << 4, kt = (rem & 15) << 4;
    const int tid = threadIdx.x, isbf = flags[0];
    for (int idx = tid; idx < 4096; idx += 256) {
        const int row = idx >> 8, col = idx & 255;
        As[row][col] = ldf(wih, (size_t)(rt + row) * 256 + col, isbf);
        Bs[row][col] = ldf(w, (size_t)l * 65536 + (size_t)(kt + row) * 256 + col, isbf);
    }
    __syncthreads();
    const int ri = tid >> 4, ki = tid & 15;
    float acc = 0.f;
    for (int j = 0; j < 256; ++j) acc = fmaf(As[ri][j], Bs[ki][j], acc);
    wihp[((size_t)l * 768 + rt + ri) * 256 + kt + ki] = acc;
}

// Build tiled gate-B matrices + biases.
// BgA[l] [1024 out][512 k] (k segs = S hi / S lo), out col j: g=(j>>4)&3,
//   b=16*(j>>6)+(j&15): g in {r,z,ni}: WihP[l][g*256+b][kk]; nh: 0.
// BgB (shared) [1024 out][512 k] (k segs = h hi / h lo): g in {r,z}:
//   Whh[g*256+b][kk]; nh: Whh[512+b][kk]; ni: 0.
__global__ void prep2_k(const float* __restrict__ wihp, const void* whh,
                        const void* bih, const void* bhh,
                        ushort* BgAH, ushort* BgAL, ushort* BgBH, ushort* BgBL,
                        float* bsum, float* bni, float* bnh,
                        const int* flags, int L) {
    const int i = blockIdx.x * blockDim.x + threadIdx.x;
    const int isbf = flags[0];
    if (i < (L << 19)) {
        const int l = i >> 19, r2 = i & 524287;
        const int j = r2 >> 9, k = r2 & 511;
        const int g = (j >> 4) & 3, b = ((j >> 6) << 4) + (j & 15);
        const int kk = k & 255;
        const float v = (g == 3) ? 0.f
                      : wihp[((size_t)l * 768 + g * 256 + b) * 256 + kk];
        const ushort hi = f2bs(v);
        const int ct = j >> 4, c = k >> 5;
        const size_t a = (size_t)l * 524288 + (size_t)(ct * 16 + c) * 512
                       + (size_t)(((k >> 3) & 3) << 7) + ((j & 15) << 3) + (k & 7);
        BgAH[a] = hi; BgAL[a] = f2bs(v - bs2f(hi));
    }
    if (i < 524288) {
        const int j = i >> 9, k = i & 511;
        const int g = (j >> 4) & 3, b = ((j >> 6) << 4) + (j & 15);
        const int kk = k & 255;
        float v;
        if (g == 0)      v = ldf(whh, (size_t)b * 256 + kk, isbf);
        else if (g == 1) v = ldf(whh, (size_t)(256 + b) * 256 + kk, isbf);
        else if (g == 2) v = 0.f;
        else             v = ldf(whh, (size_t)(512 + b) * 256 + kk, isbf);
        const ushort hi = f2bs(v);
        const int ct = j >> 4, c = k >> 5;
        const size_t a = (size_t)(ct * 16 + c) * 512
                       + (size_t)(((k >> 3) & 3) << 7) + ((j & 15) << 3) + (k & 7);
        BgBH[a] = hi; BgBL[a] = f2bs(v - bs2f(hi));
    }
    if (i < 512) bsum[i] = ldf(bih, i, isbf) + ldf(bhh, i, isbf);
    if (i < 256) {
        bni[i] = ldf(bih, 512 + i, isbf);
        bnh[i] = ldf(bhh, 512 + i, isbf);
    }
}

// ---------------- CSR build (by dst), once per call ----------------

__global__ void zero_int_k(int* p, int n) {
    int i = blockIdx.x * blockDim.x + threadIdx.x;
    if (i < n) p[i] = 0;
}

__global__ void count_k(const void* ei, int* cnt, const int* flags, int E) {
    int e = blockIdx.x * blockDim.x + threadIdx.x;
    if (e >= E) return;
    const int* e32 = (const int*)ei;
    int d = flags[1] ? e32[2 * ((size_t)E + e)] : e32[(size_t)E + e];
    atomicAdd(&cnt[d], 1);
}

__global__ __launch_bounds__(256)
void scan1_k(const int* cnt, int* ptr, int* bsumN, int N) {
    __shared__ int s[256];
    const int t = threadIdx.x;
    const int gid = blockIdx.x * 256 + t;
    int v = (gid < N) ? cnt[gid] : 0;
    const int own = v;
    s[t] = v;
    __syncthreads();
#pragma unroll
    for (int off = 1; off < 256; off <<= 1) {
        int add = (t >= off) ? s[t - off] : 0;
        __syncthreads();
        s[t] += add;
        __syncthreads();
    }
    if (gid < N) ptr[gid] = s[t] - own;
    if (t == 255) bsumN[blockIdx.x] = s[255];
}

__global__ __launch_bounds__(256)
void scan2_k(int* bsumN, int NB) {
    __shared__ int s[256];
    __shared__ int carry;
    const int t = threadIdx.x;
    if (t == 0) carry = 0;
    __syncthreads();
    for (int base = 0; base < NB; base += 256) {
        const int i = base + t;
        int v = (i < NB) ? bsumN[i] : 0;
        const int own = v;
        s[t] = v;
        __syncthreads();
#pragma unroll
        for (int off = 1; off < 256; off <<= 1) {
            int add = (t >= off) ? s[t - off] : 0;
            __syncthreads();
            s[t] += add;
            __syncthreads();
        }
        if (i < NB) bsumN[i] = carry + s[t] - own;
        __syncthreads();
        if (t == 0) carry += s[255];
        __syncthreads();
    }
}

__global__ void scan3_k(int* ptr, int* cursor, const int* bsumN, int N, int E) {
    const int gid = blockIdx.x * 256 + threadIdx.x;
    if (gid < N) {
        const int p = ptr[gid] + bsumN[blockIdx.x];
        ptr[gid] = p;
        cursor[gid] = p;
    }
    if (gid == 0) ptr[N] = E;
}

__global__ void fill_k(const void* ei, const void* ew, int* cursor,
                       int* srcs, float* wse, const int* flags, int E) {
    int e = blockIdx.x * blockDim.x + threadIdx.x;
    if (e >= E) return;
    const int* e32 = (const int*)ei;
    int s, d;
    if (flags[1]) { s = e32[2 * (size_t)e]; d = e32[2 * ((size_t)E + e)]; }
    else          { s = e32[e];             d = e32[(size_t)E + e]; }
    const int p = atomicAdd(&cursor[d], 1);
    srcs[p] = s;
    wse[p] = ldf(ew, e, flags[0]);
}

// ---------------- SpMM gather: S[d] = sum_j w_j * h[src_j] ------------------
// Gathers h_lin (packed hi|lo, 1KB/row coalesced uint4), accumulates f32,
// writes S combined plane (hi at k, lo at 256+k), tiled layout.
__global__ __launch_bounds__(256)
void spmm_k(const uint* __restrict__ hlin, const int* __restrict__ ptr,
            const int* __restrict__ srcs, const float* __restrict__ wse,
            ushort* __restrict__ AGG, int N) {
    const int node = blockIdx.x * 4 + (threadIdx.x >> 6);
    if (node >= N) return;
    const int lane = threadIdx.x & 63;
    const int lane4 = lane << 2;
    const uint4* hl = (const uint4*)hlin;
    const int p0 = ptr[node], p1 = ptr[node + 1];
    float4 acc = make_float4(0.f, 0.f, 0.f, 0.f);
    int j = p0;
    for (; j + 1 < p1; j += 2) {
        const int s0 = srcs[j], s1 = srcs[j + 1];
        const float w0 = wse[j], w1 = wse[j + 1];
        const uint4 u0 = hl[(size_t)s0 * 64 + lane];
        const uint4 u1 = hl[(size_t)s1 * 64 + lane];
        acc.x = fmaf(w0, unpk(u0.x), acc.x); acc.y = fmaf(w0, unpk(u0.y), acc.y);
        acc.z = fmaf(w0, unpk(u0.z), acc.z); acc.w = fmaf(w0, unpk(u0.w), acc.w);
        acc.x = fmaf(w1, unpk(u1.x), acc.x); acc.y = fmaf(w1, unpk(u1.y), acc.y);
        acc.z = fmaf(w1, unpk(u1.z), acc.z); acc.w = fmaf(w1, unpk(u1.w), acc.w);
    }
    if (j < p1) {
        const int s0 = srcs[j];
        const float w0 = wse[j];
        const uint4 u0 = hl[(size_t)s0 * 64 + lane];
        acc.x = fmaf(w0, unpk(u0.x), acc.x); acc.y = fmaf(w0, unpk(u0.y), acc.y);
        acc.z = fmaf(w0, unpk(u0.z), acc.z); acc.w = fmaf(w0, unpk(u0.w), acc.w);
    }
    ushort4 hi, lo;
    hi.x = f2bs(acc.x); lo.x = f2bs(acc.x - bs2f(hi.x));
    hi.y = f2bs(acc.y); lo.y = f2bs(acc.y - bs2f(hi.y));
    hi.z = f2bs(acc.z); lo.z = f2bs(acc.z - bs2f(hi.z));
    hi.w = f2bs(acc.w); lo.w = f2bs(acc.w - bs2f(hi.w));
    *(ushort4*)&AGG[taddrA(node, lane4)] = hi;
    *(ushort4*)&AGG[taddrA(node, 256 + lane4)] = lo;
}

// ---------------- gates GEMM + fused GRU (R12 BK=64 2-slab structure) -------
// A = [S hi (c0..7) | S lo (c8..15) | hH (c16..23) | hL (c24..31)].
// B = BgA[l] for c<16 (K=512, 16 chunks), BgB shared for c>=16.
// Wave's 4 col-tiles = (r,z,ni,nh) for 16 hidden units -> local GRU epilogue.
// JSKIP=3 (nh zero on S segs), JSKIP=2 (ni zero on h segs); lo-B only on
// A-hi regions (skip lo*lo). B next-ct-row stride = 16*512 = 8192.
__global__ __launch_bounds__(256)
void gates_k(const ushort* __restrict__ AGG,
             const ushort* __restrict__ HH, const ushort* __restrict__ HL,
             const ushort* __restrict__ BgAH, const ushort* __restrict__ BgAL,
             const ushort* __restrict__ BgBH, const ushort* __restrict__ BgBL,
             const float* __restrict__ bsum, const float* __restrict__ bni,
             const float* __restrict__ bnh,
             ushort* __restrict__ HnH, ushort* __restrict__ HnL,
             uint* __restrict__ hlin,
             const int* __restrict__ flags, int useHL, int nRB) {
    __shared__ ushort lds[24576];  // 2 slabs x (A 4096 | Bh 4096 | Bl 4096)
    const int x = blockIdx.x & 7, rem = blockIdx.x >> 3;
    const int cgB = rem & 7, rbHi = rem >> 3;
    const int rb = rbHi * 8 + x;
    if (rb >= nRB) return;
    const int tid = threadIdx.x, lane = tid & 63;
    const int wv = __builtin_amdgcn_readfirstlane(tid >> 6);
    const int wr = wv & 1, wc = wv >> 1;
    const int lm = lane & 15, lq = lane >> 4;
    const int fullsplit = !flags[0];
    const int rt = rb * 8, t0 = 2 * wv;
    f32x4 acc[4][4];
#pragma unroll
    for (int i = 0; i < 4; ++i)
#pragma unroll
        for (int j = 0; j < 4; ++j) acc[i][j] = (f32x4){0.f, 0.f, 0.f, 0.f};

// One BK=64 step = local chunks c0l, c0l+1 of B matrix {BH,BL} (NC=16).
#define GT_STEP(BH, BL, c0l, A0, ASTRIDE, JSKIP, DOLO)                         \
    do {                                                                       \
        __syncthreads();                                                       \
        GLD16((A0) + (size_t)lane * 8, &lds[t0 * 512]);                        \
        GLD16((A0) + (ASTRIDE) + (size_t)lane * 8, &lds[t0 * 512 + 512]);      \
        GLD16((A0) + 512 + (size_t)lane * 8, &lds[12288 + t0 * 512]);          \
        GLD16((A0) + (ASTRIDE) + 512 + (size_t)lane * 8, &lds[12288 + t0 * 512 + 512]); \
        const size_t bb = ((size_t)(8 * cgB + t0) * 16 + (size_t)(c0l)) * 512; \
        if ((t0 & 3) != (JSKIP)) {                                             \
            GLD16((BH) + bb + (size_t)lane * 8, &lds[4096 + t0 * 512]);        \
            GLD16((BH) + bb + 512 + (size_t)lane * 8, &lds[12288 + 4096 + t0 * 512]); \
        }                                                                      \
        if (((t0 + 1) & 3) != (JSKIP)) {                                       \
            GLD16((BH) + bb + 8192 + (size_t)lane * 8, &lds[4096 + t0 * 512 + 512]); \
            GLD16((BH) + bb + 8704 + (size_t)lane * 8, &lds[12288 + 4096 + t0 * 512 + 512]); \
        }                                                                      \
        if (DOLO) {                                                            \
            if ((t0 & 3) != (JSKIP)) {                                         \
                GLD16((BL) + bb + (size_t)lane * 8, &lds[8192 + t0 * 512]);    \
                GLD16((BL) + bb + 512 + (size_t)lane * 8, &lds[12288 + 8192 + t0 * 512]); \
            }                                                                  \
            if (((t0 + 1) & 3) != (JSKIP)) {                                   \
                GLD16((BL) + bb + 8192 + (size_t)lane * 8, &lds[8192 + t0 * 512 + 512]); \
                GLD16((BL) + bb + 8704 + (size_t)lane * 8, &lds[12288 + 8192 + t0 * 512 + 512]); \
            }                                                                  \
        }                                                                      \
        __syncthreads();                                                       \
        _Pragma("unroll")                                                      \
        for (int sb = 0; sb < 2; ++sb) {                                       \
            const int lb = sb * 12288;                                         \
            bf16x8 af[4];                                                      \
            _Pragma("unroll")                                                  \
            for (int i = 0; i < 4; ++i)                                        \
                af[i] = ldfrag(&lds[lb + (4 * wr + i) * 512 + lq * 128 + lm * 8]); \
            _Pragma("unroll")                                                  \
            for (int j = 0; j < 4; ++j) {                                      \
                if (j == (JSKIP)) continue;                                    \
                const bf16x8 bj = ldfrag(&lds[lb + 4096 + (4 * wc + j) * 512 + lq * 128 + lm * 8]); \
                _Pragma("unroll")                                              \
                for (int i = 0; i < 4; ++i) acc[i][j] = MFMA(af[i], bj, acc[i][j]); \
            }                                                                  \
            if (DOLO) {                                                        \
                _Pragma("unroll")                                              \
                for (int j = 0; j < 4; ++j) {                                  \
                    if (j == (JSKIP)) continue;                                \
                    const bf16x8 bl = ldfrag(&lds[lb + 8192 + (4 * wc + j) * 512 + lq * 128 + lm * 8]); \
                    _Pragma("unroll")                                          \
                    for (int i = 0; i < 4; ++i) acc[i][j] = MFMA(af[i], bl, acc[i][j]); \
                }                                                              \
            }                                                                  \
        }                                                                      \
    } while (0)

    // region 0: chunks 0..7   A = S hi (lo-B if fullsplit)
    for (int s = 0; s < 4; ++s) {
        const ushort* a0 = AGG + (size_t)(rt + t0) * 8192 + (size_t)(2 * s) * 512;
        GT_STEP(BgAH, BgAL, 2 * s, a0, 8192, 3, fullsplit);
    }
    // region 1: chunks 8..15  A = S lo (no lo-B: lo*lo dropped)
    for (int s = 4; s < 8; ++s) {
        const ushort* a0 = AGG + (size_t)(rt + t0) * 8192 + (size_t)(2 * s) * 512;
        GT_STEP(BgAH, BgAL, 2 * s, a0, 8192, 3, 0);
    }
    // region 2: chunks 16..23 A = hH (lo-B if fullsplit)
    for (int s = 8; s < 12; ++s) {
        const ushort* a0 = HH + (size_t)(rt + t0) * 4096 + (size_t)(2 * s - 16) * 512;
        GT_STEP(BgBH, BgBL, 2 * s - 16, a0, 4096, 2, fullsplit);
    }
    // region 3: chunks 24..31 A = hL (no lo-B)
    if (useHL) {
        for (int s = 12; s < 16; ++s) {
            const ushort* a0 = HL + (size_t)(rt + t0) * 4096 + (size_t)(2 * s - 24) * 512;
            GT_STEP(BgBH, BgBL, 2 * s - 16, a0, 4096, 2, 0);
        }
    }
#undef GT_STEP

    // GRU epilogue: col-tile 0..3 = r,z,ni,nh for hidden unit b
    const int b = (2 * cgB + wc) * 16 + lm;
    const float rbias = bsum[b], zbias = bsum[256 + b];
    const float ibias = bni[b], hbias = bnh[b];
#pragma unroll
    for (int i = 0; i < 4; ++i) {
        const int row0 = rb * 128 + wr * 64 + i * 16 + lq * 4;
#pragma unroll
        for (int v = 0; v < 4; ++v) {
            const int row = row0 + v;
            const size_t ho = taddrH(row, b);  // buffers padded; pads benign
            float hold = bs2f(HH[ho]);
            if (useHL) hold += bs2f(HL[ho]);
            const float r = 1.f / (1.f + expf(-(acc[i][0][v] + rbias)));
            const float z = 1.f / (1.f + expf(-(acc[i][1][v] + zbias)));
            const float nn = tanhf(acc[i][2][v] + ibias + r * (acc[i][3][v] + hbias));
            const float hv = (1.f - z) * nn + z * hold;
            const ushort hi = f2bs(hv);
            HnH[ho] = hi;
            if (useHL) HnL[ho] = f2bs(hv - bs2f(hi));
            hlin[(size_t)row * 256 + b] = (uint)hi | ((uint)f2bs(hv - bs2f(hi)) << 16);
        }
    }
}

// out[n] = sum_t relu(h[n,t]) * fc_w[t] + fc_b ; one 256-thread block per node
__global__ void final_k(const ushort* __restrict__ HH, const ushort* __restrict__ HL,
                        const void* fcw, const void* fcb,
                        void* out, const int* flags, int useHL, int N) {
    const int n = blockIdx.x;
    const int t = threadIdx.x;
    const int isbf = flags[0];
    const size_t off = taddrH(n, t);
    float h = bs2f(HH[off]);
    if (useHL) h += bs2f(HL[off]);
    float v = fmaxf(h, 0.f) * ldf(fcw, t, isbf);
#pragma unroll
    for (int offx = 32; offx >= 1; offx >>= 1) v += __shfl_down(v, offx);
    __shared__ float red[4];
    if ((t & 63) == 0) red[t >> 6] = v;
    __syncthreads();
    if (t == 0) {
        const float s = red[0] + red[1] + red[2] + red[3] + ldf(fcb, 0, isbf);
        if (isbf) ((__hip_bfloat16*)out)[n] = __float2bfloat16(s);
        else      ((float*)out)[n] = s;
    }
}

extern "C" void kernel_launch(void* const* d_in, const int* in_sizes, int n_in,
                              void* d_out, int out_size, void* d_ws, size_t ws_size,
                              hipStream_t stream) {
    const int H = HDIM;
    const int N = in_sizes[0] / H;       // 50000
    const int E = in_sizes[2];           // 800000
    const int L = in_sizes[3] / (H * H); // 5
    const int NB = (N + 255) / 256;
    const int nRB = (N + 127) / 128;     // 391
    const size_t NPAD = (size_t)nRB * 128;
    const size_t hHalf = NPAD * 256;     // halves per h plane
    const size_t aggHalf = NPAD * 512;

    char* p = (char*)d_ws;
    int*    flags = (int*)p;              p += 64;
    ushort* AGG  = (ushort*)p;            p += aggHalf * 2;
    ushort* HxH  = (ushort*)p;            p += hHalf * 2;
    ushort* HyH  = (ushort*)p;            p += hHalf * 2;
    uint*   hlin = (uint*)p;              p += NPAD * 256 * 4;
    float*  wihp = (float*)p;             p += (size_t)L * 768 * 256 * 4;
    ushort* BgAH = (ushort*)p;            p += (size_t)L * 524288 * 2;
    ushort* BgAL = (ushort*)p;            p += (size_t)L * 524288 * 2;
    ushort* BgBH = (ushort*)p;            p += (size_t)524288 * 2;
    ushort* BgBL = (ushort*)p;            p += (size_t)524288 * 2;
    float*  bsum = (float*)p;             p += 512 * 4;
    float*  bni  = (float*)p;             p += 256 * 4;
    float*  bnh  = (float*)p;             p += 256 * 4;
    int*    ptr  = (int*)p;               p += (size_t)(N + 1) * 4;
    int*    cursor = (int*)p;             p += (size_t)N * 4;
    int*    bsumN  = (int*)p;             p += (size_t)NB * 4;
    int*    srcs   = (int*)p;             p += (size_t)E * 4;
    float*  wse    = (float*)p;           p += (size_t)E * 4;
    const size_t need_reduced = (size_t)(p - (char*)d_ws);
    ushort* HxL = (ushort*)p;             // optional hi/lo h planes
    ushort* HyL = (ushort*)(p + hHalf * 2);
    const size_t need_full = need_reduced + 2 * hHalf * 2;
    const int useHL = (ws_size >= need_full) ? 1 : 0;
    if (!useHL) { HxL = HxH; HyL = HyH; }  // never dereferenced when useHL=0

    detect_k<<<dim3(1), dim3(64), 0, stream>>>(d_in[0], d_in[1], flags);
    conv_h0_k<<<dim3((unsigned)NPAD), dim3(256), 0, stream>>>(
        d_in[0], HxH, HxL, hlin, flags, useHL, N, NPAD * 256);
    prep1_k<<<dim3((unsigned)(L * 768)), dim3(256), 0, stream>>>(
        d_in[4], d_in[3], wihp, flags);
    prep2_k<<<dim3((unsigned)(L * 2048)), dim3(256), 0, stream>>>(
        wihp, d_in[5], d_in[6], d_in[7],
        BgAH, BgAL, BgBH, BgBL, bsum, bni, bnh, flags, L);

    zero_int_k<<<dim3(NB), dim3(256), 0, stream>>>(cursor, N);
    count_k<<<dim3((E + 255) / 256), dim3(256), 0, stream>>>(d_in[1], cursor, flags, E);
    scan1_k<<<dim3(NB), dim3(256), 0, stream>>>(cursor, ptr, bsumN, N);
    scan2_k<<<dim3(1), dim3(256), 0, stream>>>(bsumN, NB);
    scan3_k<<<dim3(NB), dim3(256), 0, stream>>>(ptr, cursor, bsumN, N, E);
    fill_k<<<dim3((E + 255) / 256), dim3(256), 0, stream>>>(
        d_in[1], d_in[2], cursor, srcs, wse, flags, E);

    const dim3 blk(256);
    const unsigned gGrid = 64u * (unsigned)((nRB + 7) / 8);
    ushort *HcH = HxH, *HcL = HxL, *HnH = HyH, *HnL = HyL;
    for (int l = 0; l < L; ++l) {
        spmm_k<<<dim3((N + 3) / 4), blk, 0, stream>>>(hlin, ptr, srcs, wse, AGG, N);
        gates_k<<<dim3(gGrid), blk, 0, stream>>>(
            AGG, HcH, HcL,
            BgAH + (size_t)l * 524288, BgAL + (size_t)l * 524288,
            BgBH, BgBL, bsum, bni, bnh, HnH, HnL, hlin, flags, useHL, nRB);
        ushort* t;
        t = HcH; HcH = HnH; HnH = t;
        t = HcL; HcL = HnL; HnL = t;
    }
    final_k<<<dim3(N), blk, 0, stream>>>(
        HcH, HcL, d_in[8], d_in[9], d_out, flags, useHL, N);
}